// Round 1
// baseline (1011.534 us; speedup 1.0000x reference)
//
#include <hip/hip_runtime.h>
#include <hip/hip_bf16.h>

#define NB   32
#define TQn  2048
#define TKn  2048
#define TAGD 128
#define ENCD 256
#define ATTD 128

using bf16x8 = __attribute__((ext_vector_type(8))) __bf16;
using f32x4  = __attribute__((ext_vector_type(4))) float;

__device__ __forceinline__ bf16x8 cvt8(float4 p0, float4 p1) {
    bf16x8 r;
    r[0] = (__bf16)p0.x; r[1] = (__bf16)p0.y; r[2] = (__bf16)p0.z; r[3] = (__bf16)p0.w;
    r[4] = (__bf16)p1.x; r[5] = (__bf16)p1.y; r[6] = (__bf16)p1.z; r[7] = (__bf16)p1.w;
    return r;
}

// ---------------------------------------------------------------------------
// Kernel A: k/v projections.  out[row, j] = sum_e in[row, e] * W[j, e] + bias[j]
// grid (1024, 2): x = 64-row block, y selects (key,Wk,bk)->kproj vs (value,Wv,bv)->vproj
// Also zeroes colsum (folded memset: sel==0 blocks 0..63 clear 1024 floats each).
// ---------------------------------------------------------------------------
__global__ __launch_bounds__(256) void proj_kernel(
    const float* __restrict__ key, const float* __restrict__ value,
    const float* __restrict__ Wk, const float* __restrict__ bk,
    const float* __restrict__ Wv, const float* __restrict__ bv,
    __bf16* __restrict__ kproj, __bf16* __restrict__ vproj,
    float* __restrict__ colsum)
{
    const int sel = blockIdx.y;

    // folded colsum zeroing: 64 blocks x 256 thr x 4 = 65536 floats
    if (sel == 0 && blockIdx.x < 64) {
        float* cs = colsum + (blockIdx.x << 10);
        #pragma unroll
        for (int i = 0; i < 4; ++i) cs[i * 256 + threadIdx.x] = 0.0f;
    }

    const float* in   = sel ? value : key;
    const float* W    = sel ? Wv : Wk;
    const float* bias = sel ? bv : bk;
    __bf16* out       = sel ? vproj : kproj;

    const int tid  = threadIdx.x;
    const int w    = tid >> 6;
    const int lane = tid & 63;
    const int qd   = lane >> 4;
    const int ln   = lane & 15;
    const int r0   = blockIdx.x * 64 + w * 16;

    // A fragments: row r0+ln, k = 32s + 8qd .. +8
    bf16x8 afrag[8];
    {
        const float* arow = in + (size_t)(r0 + ln) * ENCD + 8 * qd;
        #pragma unroll
        for (int s = 0; s < 8; ++s) {
            float4 p0 = *(const float4*)(arow + 32 * s);
            float4 p1 = *(const float4*)(arow + 32 * s + 4);
            afrag[s] = cvt8(p0, p1);
        }
    }

    #pragma unroll
    for (int ct = 0; ct < 8; ++ct) {
        f32x4 acc = {0.f, 0.f, 0.f, 0.f};
        const float* wrow = W + (size_t)(ct * 16 + ln) * ENCD + 8 * qd;
        #pragma unroll
        for (int s = 0; s < 8; ++s) {
            float4 p0 = *(const float4*)(wrow + 32 * s);
            float4 p1 = *(const float4*)(wrow + 32 * s + 4);
            bf16x8 bfrag = cvt8(p0, p1);
            acc = __builtin_amdgcn_mfma_f32_16x16x32_bf16(afrag[s], bfrag, acc, 0, 0, 0);
        }
        const float bb = bias[ct * 16 + ln];
        #pragma unroll
        for (int r = 0; r < 4; ++r) {
            const int row = r0 + 4 * qd + r;           // C/D: col=lane&15, row=4*quad+reg
            out[(size_t)row * ATTD + ct * 16 + ln] = (__bf16)(acc[r] + bb);
        }
    }
}

// ---------------------------------------------------------------------------
// Kernel B: score = softmax(query @ kproj^T) -> score; column sums -> colsum.
// One block = (b, 64 q-rows), 256 thr. Two register-only passes over k
// (constant shift 20 instead of row max).
//
// SWAPPED MFMA OPERANDS: mfma(kf, qf) so C/D lane (qd,ln), reg r holds
// dot(q-row = rg*16+ln, k-col = col0 + 4*qd + r)  ->  each lane owns 4
// CONSECUTIVE columns of ONE row: float4 nontemporal stores (4 instr per
// (ch,cti) instead of 16), and row-state (lpart/linv) is 4 scalars not 16.
//
// XCD swizzle: 1024 blocks % 8 XCDs == 0; each XCD gets 4 whole batches so
// kproj[b] is fetched from HBM into exactly one L2.
// ---------------------------------------------------------------------------
__global__ __launch_bounds__(256) void attn_kernel(
    const float* __restrict__ query,   // [NB, TQn, TAGD]
    const __bf16* __restrict__ kproj,  // [NB, TKn, ATTD]
    float* __restrict__ score,         // [NB, TQn, TKn]
    float* __restrict__ colsum)        // [NB, TKn]
{
    const int bid = ((blockIdx.x & 7) << 7) | (blockIdx.x >> 3);  // bijective, 1024%8==0
    const int b   = bid >> 5;
    const int q0  = (bid & 31) * 64;
    const int tid = threadIdx.x;
    const int w    = tid >> 6;
    const int lane = tid & 63;
    const int qd   = lane >> 4;
    const int ln   = lane & 15;

    __shared__ float lred[4][64];

    // A fragments (B-operand after swap): 4 row-groups x 4 k-steps, row q0+rg*16+ln
    bf16x8 a[4][4];
    #pragma unroll
    for (int rg = 0; rg < 4; ++rg) {
        const float* qrow = query + ((size_t)b * TQn + q0 + rg * 16 + ln) * TAGD + 8 * qd;
        #pragma unroll
        for (int s = 0; s < 4; ++s) {
            float4 p0 = *(const float4*)(qrow + 32 * s);
            float4 p1 = *(const float4*)(qrow + 32 * s + 4);
            a[rg][s] = cvt8(p0, p1);
        }
    }

    const __bf16* kb = kproj + (size_t)b * TKn * ATTD;

    // ---- pass 1: row sums of exp(dot - 20) ----
    float lpart[4] = {0.f, 0.f, 0.f, 0.f};
    for (int ch = 0; ch < 16; ++ch) {
        #pragma unroll
        for (int cti = 0; cti < 2; ++cti) {
            const int col0 = ch * 128 + w * 32 + cti * 16;   // wave owns 32 adjacent cols
            const __bf16* krow = kb + (size_t)(col0 + ln) * ATTD + 8 * qd;
            bf16x8 kf[4];
            #pragma unroll
            for (int s = 0; s < 4; ++s) kf[s] = *(const bf16x8*)(krow + 32 * s);
            #pragma unroll
            for (int rg = 0; rg < 4; ++rg) {
                f32x4 acc = {0.f, 0.f, 0.f, 0.f};
                #pragma unroll
                for (int s = 0; s < 4; ++s)
                    acc = __builtin_amdgcn_mfma_f32_16x16x32_bf16(kf[s], a[rg][s], acc, 0, 0, 0);
                lpart[rg] += __expf(acc[0] - 20.0f) + __expf(acc[1] - 20.0f)
                           + __expf(acc[2] - 20.0f) + __expf(acc[3] - 20.0f);
            }
        }
    }

    // reduce partial row-sums across the 4 qd-groups, then across waves via LDS
    #pragma unroll
    for (int rg = 0; rg < 4; ++rg) {
        float v = lpart[rg];
        v += __shfl_xor(v, 16);
        v += __shfl_xor(v, 32);
        lpart[rg] = v;
    }
    if (qd == 0) {
        #pragma unroll
        for (int rg = 0; rg < 4; ++rg) lred[w][rg * 16 + ln] = lpart[rg];
    }
    __syncthreads();

    float linv[4];
    #pragma unroll
    for (int rg = 0; rg < 4; ++rg) {
        const int row = rg * 16 + ln;
        linv[rg] = 1.0f / (lred[0][row] + lred[1][row] + lred[2][row] + lred[3][row]);
    }

    // ---- pass 2: recompute dot, normalize, float4-store score, accumulate colsum ----
    float* srow_base = score + ((size_t)b * TQn + q0) * (size_t)TKn;
    for (int ch = 0; ch < 16; ++ch) {
        #pragma unroll
        for (int cti = 0; cti < 2; ++cti) {
            const int col0 = ch * 128 + w * 32 + cti * 16;
            const __bf16* krow = kb + (size_t)(col0 + ln) * ATTD + 8 * qd;
            bf16x8 kf[4];
            #pragma unroll
            for (int s = 0; s < 4; ++s) kf[s] = *(const bf16x8*)(krow + 32 * s);
            float cs0 = 0.f, cs1 = 0.f, cs2 = 0.f, cs3 = 0.f;
            #pragma unroll
            for (int rg = 0; rg < 4; ++rg) {
                f32x4 acc = {0.f, 0.f, 0.f, 0.f};
                #pragma unroll
                for (int s = 0; s < 4; ++s)
                    acc = __builtin_amdgcn_mfma_f32_16x16x32_bf16(kf[s], a[rg][s], acc, 0, 0, 0);
                f32x4 p;
                p[0] = __expf(acc[0] - 20.0f) * linv[rg];
                p[1] = __expf(acc[1] - 20.0f) * linv[rg];
                p[2] = __expf(acc[2] - 20.0f) * linv[rg];
                p[3] = __expf(acc[3] - 20.0f) * linv[rg];
                cs0 += p[0]; cs1 += p[1]; cs2 += p[2]; cs3 += p[3];
                __builtin_nontemporal_store(p,
                    (f32x4*)(srow_base + (size_t)(rg * 16 + ln) * TKn + col0 + 4 * qd));
            }
            // column sums: reduce over the 16 q-rows held in ln-lanes
            #pragma unroll
            for (int m = 1; m < 16; m <<= 1) {
                cs0 += __shfl_xor(cs0, m);
                cs1 += __shfl_xor(cs1, m);
                cs2 += __shfl_xor(cs2, m);
                cs3 += __shfl_xor(cs3, m);
            }
            if (ln == 0) {
                float* cp = &colsum[b * TKn + col0 + 4 * qd];
                atomicAdd(cp + 0, cs0);
                atomicAdd(cp + 1, cs1);
                atomicAdd(cp + 2, cs2);
                atomicAdd(cp + 3, cs3);
            }
        }
    }
}

// ---------------------------------------------------------------------------
// Kernel C: att_res[b,d] = (1/TQ) * sum_k colsum[b,k] * vproj[b,k,d]
// ---------------------------------------------------------------------------
__global__ __launch_bounds__(512) void outmean_kernel(
    const float* __restrict__ colsum, const __bf16* __restrict__ vproj,
    float* __restrict__ att)
{
    const int b  = blockIdx.x;
    const int d  = threadIdx.x & 127;
    const int kq = threadIdx.x >> 7;    // 0..3
    __shared__ float red[512];

    const __bf16* vb = vproj + (size_t)b * TKn * ATTD;
    const float* cs  = colsum + b * TKn;
    float acc = 0.f;
    for (int k = kq * 512; k < kq * 512 + 512; ++k)
        acc += cs[k] * (float)vb[(size_t)k * ATTD + d];

    red[threadIdx.x] = acc;
    __syncthreads();
    if (kq == 0) {
        const float t = acc + red[threadIdx.x + 128] + red[threadIdx.x + 256] + red[threadIdx.x + 384];
        att[b * ATTD + d] = t * (1.0f / (float)TQn);
    }
}

extern "C" void kernel_launch(void* const* d_in, const int* in_sizes, int n_in,
                              void* d_out, int out_size, void* d_ws, size_t ws_size,
                              hipStream_t stream) {
    const float* query = (const float*)d_in[0];
    const float* key   = (const float*)d_in[1];
    const float* value = (const float*)d_in[2];
    // d_in[3] = Wq, d_in[4] = bq : dead in the reference (output unused)
    const float* Wk    = (const float*)d_in[5];
    const float* bk    = (const float*)d_in[6];
    const float* Wv    = (const float*)d_in[7];
    const float* bv    = (const float*)d_in[8];

    float* att   = (float*)d_out;                       // [32, 128]
    float* score = att + (size_t)NB * ATTD;             // [32, 2048, 2048]

    char* ws = (char*)d_ws;
    __bf16* kproj = (__bf16*)ws;                                   // 16 MB
    __bf16* vproj = (__bf16*)(ws + (size_t)16 * 1024 * 1024);      // 16 MB
    float*  colsum = (float*)(ws + (size_t)32 * 1024 * 1024);      // 256 KB

    proj_kernel<<<dim3(1024, 2), 256, 0, stream>>>(key, value, Wk, bk, Wv, bv, kproj, vproj, colsum);
    attn_kernel<<<dim3(NB * (TQn / 64)), 256, 0, stream>>>(query, kproj, score, colsum);
    outmean_kernel<<<dim3(NB), 512, 0, stream>>>(colsum, vproj, att);
}

// Round 2
// 979.937 us; speedup vs baseline: 1.0322x; 1.0322x over previous
//
#include <hip/hip_runtime.h>
#include <hip/hip_bf16.h>

#define NB   32
#define TQn  2048
#define TKn  2048
#define TAGD 128
#define ENCD 256
#define ATTD 128

using bf16x8 = __attribute__((ext_vector_type(8))) __bf16;
using f32x4  = __attribute__((ext_vector_type(4))) float;

__device__ __forceinline__ bf16x8 cvt8(float4 p0, float4 p1) {
    bf16x8 r;
    r[0] = (__bf16)p0.x; r[1] = (__bf16)p0.y; r[2] = (__bf16)p0.z; r[3] = (__bf16)p0.w;
    r[4] = (__bf16)p1.x; r[5] = (__bf16)p1.y; r[6] = (__bf16)p1.z; r[7] = (__bf16)p1.w;
    return r;
}

// ---------------------------------------------------------------------------
// Kernel A: k/v projections.  out[row, j] = sum_e in[row, e] * W[j, e] + bias[j]
// grid (1024, 2): x = 64-row block, y selects (key,Wk,bk)->kproj vs (value,Wv,bv)->vproj
// ---------------------------------------------------------------------------
__global__ __launch_bounds__(256) void proj_kernel(
    const float* __restrict__ key, const float* __restrict__ value,
    const float* __restrict__ Wk, const float* __restrict__ bk,
    const float* __restrict__ Wv, const float* __restrict__ bv,
    __bf16* __restrict__ kproj, __bf16* __restrict__ vproj)
{
    const int sel = blockIdx.y;
    const float* in   = sel ? value : key;
    const float* W    = sel ? Wv : Wk;
    const float* bias = sel ? bv : bk;
    __bf16* out       = sel ? vproj : kproj;

    const int tid  = threadIdx.x;
    const int w    = tid >> 6;
    const int lane = tid & 63;
    const int qd   = lane >> 4;
    const int ln   = lane & 15;
    const int r0   = blockIdx.x * 64 + w * 16;

    // A fragments: row r0+ln, k = 32s + 8qd .. +8
    bf16x8 afrag[8];
    {
        const float* arow = in + (size_t)(r0 + ln) * ENCD + 8 * qd;
        #pragma unroll
        for (int s = 0; s < 8; ++s) {
            float4 p0 = *(const float4*)(arow + 32 * s);
            float4 p1 = *(const float4*)(arow + 32 * s + 4);
            afrag[s] = cvt8(p0, p1);
        }
    }

    #pragma unroll
    for (int ct = 0; ct < 8; ++ct) {
        f32x4 acc = {0.f, 0.f, 0.f, 0.f};
        const float* wrow = W + (size_t)(ct * 16 + ln) * ENCD + 8 * qd;
        #pragma unroll
        for (int s = 0; s < 8; ++s) {
            float4 p0 = *(const float4*)(wrow + 32 * s);
            float4 p1 = *(const float4*)(wrow + 32 * s + 4);
            bf16x8 bfrag = cvt8(p0, p1);
            acc = __builtin_amdgcn_mfma_f32_16x16x32_bf16(afrag[s], bfrag, acc, 0, 0, 0);
        }
        const float bb = bias[ct * 16 + ln];
        #pragma unroll
        for (int r = 0; r < 4; ++r) {
            const int row = r0 + 4 * qd + r;           // C/D: col=lane&15, row=4*quad+reg
            out[(size_t)row * ATTD + ct * 16 + ln] = (__bf16)(acc[r] + bb);
        }
    }
}

// ---------------------------------------------------------------------------
// Kernel B: score = softmax(query @ kproj^T) -> score; per-qblock column-sum
// partials -> qpart[b][qblk][TKn] (plain stores, NO atomics).
// One block = (b, 64 q-rows), 256 thr. Two register-only passes over k.
//
// Swapped MFMA operands: mfma(kf, qf) -> lane (qd,ln), reg r holds
// dot(q-row = rg*16+ln, k-col = col0 + 4*qd + r): float4 score stores.
//
// Constant shift folded into MFMA C-init (acc starts at -20); in pass 2 the
// row normalizer is ALSO folded in (acc starts at -20 - log(l_row)), so the
// per-element work is exactly {fma, v_exp} + colsum add.
// ---------------------------------------------------------------------------
__global__ __launch_bounds__(256) void attn_kernel(
    const float* __restrict__ query,   // [NB, TQn, TAGD]
    const __bf16* __restrict__ kproj,  // [NB, TKn, ATTD]
    float* __restrict__ score,         // [NB, TQn, TKn]
    float* __restrict__ qpart)         // [NB, 32, TKn]
{
    const int bid = ((blockIdx.x & 7) << 7) | (blockIdx.x >> 3);  // bijective, 1024%8==0
    const int b    = bid >> 5;
    const int qblk = bid & 31;
    const int q0   = qblk * 64;
    const int tid  = threadIdx.x;
    const int w    = tid >> 6;
    const int lane = tid & 63;
    const int qd   = lane >> 4;
    const int ln   = lane & 15;

    __shared__ float lred[4][64];

    // Q fragments (B-operand after swap): 4 row-groups x 4 k-steps, row q0+rg*16+ln
    bf16x8 a[4][4];
    #pragma unroll
    for (int rg = 0; rg < 4; ++rg) {
        const float* qrow = query + ((size_t)b * TQn + q0 + rg * 16 + ln) * TAGD + 8 * qd;
        #pragma unroll
        for (int s = 0; s < 4; ++s) {
            float4 p0 = *(const float4*)(qrow + 32 * s);
            float4 p1 = *(const float4*)(qrow + 32 * s + 4);
            a[rg][s] = cvt8(p0, p1);
        }
    }

    const __bf16* kb = kproj + (size_t)b * TKn * ATTD;

    // ---- pass 1: row sums of exp(dot - 20); shift folded into C-init ----
    float lpart[4] = {0.f, 0.f, 0.f, 0.f};
    for (int ch = 0; ch < 16; ++ch) {
        #pragma unroll
        for (int cti = 0; cti < 2; ++cti) {
            const int col0 = ch * 128 + w * 32 + cti * 16;
            const __bf16* krow = kb + (size_t)(col0 + ln) * ATTD + 8 * qd;
            bf16x8 kf[4];
            #pragma unroll
            for (int s = 0; s < 4; ++s) kf[s] = *(const bf16x8*)(krow + 32 * s);
            #pragma unroll
            for (int rg = 0; rg < 4; ++rg) {
                f32x4 acc = {-20.f, -20.f, -20.f, -20.f};
                #pragma unroll
                for (int s = 0; s < 4; ++s)
                    acc = __builtin_amdgcn_mfma_f32_16x16x32_bf16(kf[s], a[rg][s], acc, 0, 0, 0);
                lpart[rg] += (__expf(acc[0]) + __expf(acc[1]))
                           + (__expf(acc[2]) + __expf(acc[3]));
            }
        }
    }

    // reduce partial row-sums across the 4 qd-groups, then across waves via LDS
    #pragma unroll
    for (int rg = 0; rg < 4; ++rg) {
        float v = lpart[rg];
        v += __shfl_xor(v, 16);
        v += __shfl_xor(v, 32);
        lpart[rg] = v;
    }
    if (qd == 0) {
        #pragma unroll
        for (int rg = 0; rg < 4; ++rg) lred[w][rg * 16 + ln] = lpart[rg];
    }
    __syncthreads();

    // per-row exponent offset: -20 - log(l_row)  (folds normalization into exp)
    float crg[4];
    #pragma unroll
    for (int rg = 0; rg < 4; ++rg) {
        const int row = rg * 16 + ln;
        const float l = lred[0][row] + lred[1][row] + lred[2][row] + lred[3][row];
        crg[rg] = -20.f - __logf(l);
    }

    // ---- pass 2: recompute dot, exp(acc) is already normalized; float4 stores ----
    float* srow_base = score + ((size_t)b * TQn + q0) * (size_t)TKn;
    float* qp        = qpart + ((size_t)b * 32 + qblk) * (size_t)TKn;
    for (int ch = 0; ch < 16; ++ch) {
        #pragma unroll
        for (int cti = 0; cti < 2; ++cti) {
            const int col0 = ch * 128 + w * 32 + cti * 16;
            const __bf16* krow = kb + (size_t)(col0 + ln) * ATTD + 8 * qd;
            bf16x8 kf[4];
            #pragma unroll
            for (int s = 0; s < 4; ++s) kf[s] = *(const bf16x8*)(krow + 32 * s);
            float cs0 = 0.f, cs1 = 0.f, cs2 = 0.f, cs3 = 0.f;
            #pragma unroll
            for (int rg = 0; rg < 4; ++rg) {
                f32x4 acc = {crg[rg], crg[rg], crg[rg], crg[rg]};
                #pragma unroll
                for (int s = 0; s < 4; ++s)
                    acc = __builtin_amdgcn_mfma_f32_16x16x32_bf16(kf[s], a[rg][s], acc, 0, 0, 0);
                f32x4 p;
                p[0] = __expf(acc[0]);
                p[1] = __expf(acc[1]);
                p[2] = __expf(acc[2]);
                p[3] = __expf(acc[3]);
                cs0 += p[0]; cs1 += p[1]; cs2 += p[2]; cs3 += p[3];
                __builtin_nontemporal_store(p,
                    (f32x4*)(srow_base + (size_t)(rg * 16 + ln) * TKn + col0 + 4 * qd));
            }
            // column sums over the 16 q-rows held in ln-lanes (DPP-cheap masks)
            #pragma unroll
            for (int m = 1; m < 16; m <<= 1) {
                cs0 += __shfl_xor(cs0, m);
                cs1 += __shfl_xor(cs1, m);
                cs2 += __shfl_xor(cs2, m);
                cs3 += __shfl_xor(cs3, m);
            }
            if (ln == 0) {   // lanes 0,16,32,48: one dwordx4 store, disjoint slice
                f32x4 v = {cs0, cs1, cs2, cs3};
                *(f32x4*)(qp + col0 + 4 * qd) = v;
            }
        }
    }
}

// ---------------------------------------------------------------------------
// Kernel C: att_res[b,d] = (1/TQ) * sum_k (sum_qb qpart[b,qb,k]) * vproj[b,k,d]
// Stage 1: coalesced reduce of 32 partials into LDS cs[2048]; stage 2 as before.
// ---------------------------------------------------------------------------
__global__ __launch_bounds__(512) void outmean_kernel(
    const float* __restrict__ qpart, const __bf16* __restrict__ vproj,
    float* __restrict__ att)
{
    const int b  = blockIdx.x;
    const int d  = threadIdx.x & 127;
    const int kq = threadIdx.x >> 7;    // 0..3
    __shared__ float cs[TKn];           // 8 KB
    __shared__ float red[512];

    // stage 1: cs[k] = sum over 32 q-block partials (coalesced over k)
    const float* pp = qpart + (size_t)b * 32 * TKn;
    for (int k = threadIdx.x; k < TKn; k += 512) {
        float s = 0.f;
        #pragma unroll
        for (int qb = 0; qb < 32; ++qb) s += pp[(size_t)qb * TKn + k];
        cs[k] = s;
    }
    __syncthreads();

    const __bf16* vb = vproj + (size_t)b * TKn * ATTD;
    float acc = 0.f;
    for (int k = kq * 512; k < kq * 512 + 512; ++k)
        acc += cs[k] * (float)vb[(size_t)k * ATTD + d];

    red[threadIdx.x] = acc;
    __syncthreads();
    if (kq == 0) {
        const float t = acc + red[threadIdx.x + 128] + red[threadIdx.x + 256] + red[threadIdx.x + 384];
        att[b * ATTD + d] = t * (1.0f / (float)TQn);
    }
}

extern "C" void kernel_launch(void* const* d_in, const int* in_sizes, int n_in,
                              void* d_out, int out_size, void* d_ws, size_t ws_size,
                              hipStream_t stream) {
    const float* query = (const float*)d_in[0];
    const float* key   = (const float*)d_in[1];
    const float* value = (const float*)d_in[2];
    // d_in[3] = Wq, d_in[4] = bq : dead in the reference (output unused)
    const float* Wk    = (const float*)d_in[5];
    const float* bk    = (const float*)d_in[6];
    const float* Wv    = (const float*)d_in[7];
    const float* bv    = (const float*)d_in[8];

    float* att   = (float*)d_out;                       // [32, 128]
    float* score = att + (size_t)NB * ATTD;             // [32, 2048, 2048]

    char* ws = (char*)d_ws;
    __bf16* kproj = (__bf16*)ws;                                   // 16 MB
    __bf16* vproj = (__bf16*)(ws + (size_t)16 * 1024 * 1024);      // 16 MB
    float*  qpart = (float*)(ws + (size_t)32 * 1024 * 1024);       // 8 MB

    proj_kernel<<<dim3(1024, 2), 256, 0, stream>>>(key, value, Wk, bk, Wv, bv, kproj, vproj);
    attn_kernel<<<dim3(NB * (TQn / 64)), 256, 0, stream>>>(query, kproj, score, qpart);
    outmean_kernel<<<dim3(NB), 512, 0, stream>>>(qpart, vproj, att);
}